// Round 4
// baseline (257.691 us; speedup 1.0000x reference)
//
#include <hip/hip_runtime.h>

// SVConv2d: out[n,o,h,w] = sum_{ci,kh,kw} weight[o,ci,kh,kw,h,w] * x[n,ci,h+kh-1,w+kw-1] + bias[o]
// N=8, Cin=Cout=32, K=3, H=W=64. Weight (151 MB) read exactly once -> HBM-bound, floor ~25us.
// v4: 2-phase LDS pipeline (T14). All compute reads come from LDS (lgkmcnt), the global
// stream (weights HBM + x L2) is issued at the top of each ci step and drained once per
// step before the ds_write + barrier -> no false vmcnt dependencies, full latency hiding.
// Block = (o, h-pair): 256 thr / 4 waves, wave ci-loop over all 32 ci, wave <-> n-pair,
// lane <-> (hrow, w-pair). acc = 4 floats. 1024 blocks, all resident (4/CU, 16 waves/CU).

#define Nn 8
#define CI 32
#define CO 32
#define Hh 64
#define Ww 64
#define HW 4096

__global__ __launch_bounds__(256, 4) void svconv_kernel(
    const float* __restrict__ x, const float* __restrict__ wgt,
    const float* __restrict__ bias, float* __restrict__ out) {
  // w_lds[buf][plane 0..8][hrow*64 + w]
  // x_lds[buf][n][r (global row hbase-1+r)][i] with i=0..65, value = x[w=i-1] (halo zeros)
  __shared__ float w_lds[2][9][128];
  __shared__ float x_lds[2][8][4][66];

  const int tid   = threadIdx.x;
  const int o     = blockIdx.x >> 5;
  const int hbase = (blockIdx.x & 31) << 1;

  // ---- compute mapping ----
  const int ws   = tid >> 6;   // wave -> n pair {2ws, 2ws+1}
  const int lane = tid & 63;
  const int hrow = lane >> 5;  // 2 output rows per block
  const int wp   = lane & 31;  // 32 w-pairs
  const int w0   = wp << 1;

  // ---- stage mapping: W (288 float4: planes 0..7 by all threads, plane 8 by tid<32) ----
  const int  pA   = tid >> 5;       // 0..7
  const int  qA   = tid & 31;       // float4 index within 128-float slice
  const bool hasB = (tid < 32);
  const float* wgA = wgt + ((size_t)(o * CI * 9 + pA)) * HW + hbase * Ww + qA * 4;
  const float* wgB = wgt + ((size_t)(o * CI * 9 + 8)) * HW + hbase * Ww + (tid & 31) * 4;

  // ---- stage mapping: X (512 float4: 2 per thread, n = {tid>>6, tid>>6 + 4}) ----
  const int  nX0 = tid >> 6;        // 0..3
  const int  nX1 = nX0 + 4;         // 4..7
  const int  rX  = (tid >> 4) & 3;  // staged row index
  const int  qX  = tid & 15;        // float4 within row
  const int  rgX = hbase - 1 + rX;  // global row
  const bool okX = (rgX >= 0) && (rgX < Hh);
  const int  rgc = okX ? rgX : 0;
  const float* xg0 = x + (size_t)nX0 * CI * HW + rgc * Ww + qX * 4;
  const float* xg1 = x + (size_t)nX1 * CI * HW + rgc * Ww + qX * 4;

  // ---- halo zero columns (never overwritten by staging) ----
  if (tid < 128) {
    const int b = tid >> 6, n = (tid >> 3) & 7, r = (tid >> 1) & 3, side = tid & 1;
    x_lds[b][n][r][side ? 65 : 0] = 0.f;
  }

  float acc[2][2] = {{0.f, 0.f}, {0.f, 0.f}};
  float4 vwA, vwB, vx0, vx1;

  auto stage_issue = [&](int ci) {
    const size_t cw = (size_t)ci * (9 * HW);
    const size_t cx = (size_t)ci * HW;
    vwA = *(const float4*)(wgA + cw);
    if (hasB) vwB = *(const float4*)(wgB + cw);
    vx0 = *(const float4*)(xg0 + cx);
    vx1 = *(const float4*)(xg1 + cx);
  };

  auto stage_write = [&](int buf) {
    *(float4*)&w_lds[buf][pA][qA * 4] = vwA;
    if (hasB) *(float4*)&w_lds[buf][8][(tid & 31) * 4] = vwB;
    float* d0 = &x_lds[buf][nX0][rX][1 + qX * 4];
    d0[0] = okX ? vx0.x : 0.f;
    d0[1] = okX ? vx0.y : 0.f;
    d0[2] = okX ? vx0.z : 0.f;
    d0[3] = okX ? vx0.w : 0.f;
    float* d1 = &x_lds[buf][nX1][rX][1 + qX * 4];
    d1[0] = okX ? vx1.x : 0.f;
    d1[1] = okX ? vx1.y : 0.f;
    d1[2] = okX ? vx1.z : 0.f;
    d1[3] = okX ? vx1.w : 0.f;
  };

  auto compute = [&](int buf) {
    float2 wv[9];
    #pragma unroll
    for (int p = 0; p < 9; ++p)
      wv[p] = *(const float2*)&w_lds[buf][p][hrow * 64 + w0];
    #pragma unroll
    for (int nl = 0; nl < 2; ++nl) {
      const int n = ws * 2 + nl;
      #pragma unroll
      for (int kh = 0; kh < 3; ++kh) {
        float2 a = *(const float2*)&x_lds[buf][n][hrow + kh][w0];      // x[w0-1], x[w0]
        float2 b = *(const float2*)&x_lds[buf][n][hrow + kh][w0 + 2];  // x[w0+1], x[w0+2]
        acc[nl][0] = fmaf(wv[3 * kh + 0].x, a.x, acc[nl][0]);
        acc[nl][0] = fmaf(wv[3 * kh + 1].x, a.y, acc[nl][0]);
        acc[nl][0] = fmaf(wv[3 * kh + 2].x, b.x, acc[nl][0]);
        acc[nl][1] = fmaf(wv[3 * kh + 0].y, a.y, acc[nl][1]);
        acc[nl][1] = fmaf(wv[3 * kh + 1].y, b.x, acc[nl][1]);
        acc[nl][1] = fmaf(wv[3 * kh + 2].y, b.y, acc[nl][1]);
      }
    }
  };

  // ---- 2-phase pipeline over ci ----
  stage_issue(0);
  stage_write(0);
  __syncthreads();

  #pragma unroll 1
  for (int ci = 0; ci < CI; ci += 2) {
    stage_issue(ci + 1);            // ci+1 <= 31 always
    compute(0);                     // ci
    stage_write(1);
    __syncthreads();
    if (ci + 2 < CI) stage_issue(ci + 2);
    compute(1);                     // ci+1
    if (ci + 2 < CI) stage_write(0);
    __syncthreads();
  }

  const float bo = bias[o];
  #pragma unroll
  for (int nl = 0; nl < 2; ++nl) {
    float2 r;
    r.x = acc[nl][0] + bo;
    r.y = acc[nl][1] + bo;
    *(float2*)(out + ((size_t)(ws * 2 + nl) * CO + o) * HW + (hbase + hrow) * Ww + w0) = r;
  }
}

extern "C" void kernel_launch(void* const* d_in, const int* in_sizes, int n_in,
                              void* d_out, int out_size, void* d_ws, size_t ws_size,
                              hipStream_t stream) {
  const float* x    = (const float*)d_in[0];
  const float* wgt  = (const float*)d_in[1];
  const float* bias = (const float*)d_in[2];
  float* out = (float*)d_out;

  // 32 o * 32 h-pairs = 1024 blocks of 256 threads; whole grid resident (4 blocks/CU)
  dim3 grid(1024), block(256);
  svconv_kernel<<<grid, block, 0, stream>>>(x, wgt, bias, out);
}